// Round 1
// 214.091 us; speedup vs baseline: 1.0338x; 1.0338x over previous
//
#include <hip/hip_runtime.h>

typedef __attribute__((ext_vector_type(8))) short short8;
typedef __attribute__((ext_vector_type(4))) float f32x4;
typedef __attribute__((ext_vector_type(16))) float f32x16;
typedef __attribute__((ext_vector_type(2))) unsigned int u32x2;
typedef __attribute__((ext_vector_type(4))) unsigned int u32x4;
typedef unsigned short u16;
typedef unsigned int u32;

#define MFMA16(a, b, c) __builtin_amdgcn_mfma_f32_16x16x32_bf16((a), (b), (c), 0, 0, 0)
#define MFMA32(a, b, c) __builtin_amdgcn_mfma_f32_32x32x16_bf16((a), (b), (c), 0, 0, 0)

// barrier flavors: BAR_VMEM drains the async DMA (+P visibility); BAR_LDS is
// LDS-only so global prefetches stay in flight across it.
#define BAR_VMEM() asm volatile("s_waitcnt vmcnt(0) lgkmcnt(0)\ns_barrier" ::: "memory")
#define BAR_LDS()  asm volatile("s_waitcnt lgkmcnt(0)\ns_barrier" ::: "memory")

#define BATCH 8
#define NTOK 4096
#define CDIM 256
#define CQK 32
#define LOG2E 1.4426950408889634f

__device__ __forceinline__ u16 f2bf(float f) {
  u32 u = __float_as_uint(f);
  return (u16)((u + 0x7FFFu + ((u >> 16) & 1u)) >> 16);
}
// pack two f32 -> two bf16 (round-half-up) in one u32: bf(a) | bf(b)<<16
__device__ __forceinline__ u32 pack2(float a, float b) {
  const u32 ua = __float_as_uint(a) + 0x8000u;
  const u32 ub = __float_as_uint(b) + 0x8000u;
#if __has_builtin(__builtin_amdgcn_perm)
  return __builtin_amdgcn_perm(ub, ua, 0x07060302u);  // {ua.b2,ua.b3,ub.b2,ub.b3}
#else
  return (ua >> 16) | (ub & 0xFFFF0000u);
#endif
}
__device__ __forceinline__ float fexp2(float x) {
#if __has_builtin(__builtin_amdgcn_exp2f)
  return __builtin_amdgcn_exp2f(x);
#else
  return exp2f(x);
#endif
}
__device__ __forceinline__ void gl_lds16(const u16* g, u16* l) {
  __builtin_amdgcn_global_load_lds(
      (const __attribute__((address_space(1))) unsigned int*)(g),
      (__attribute__((address_space(3))) unsigned int*)(l), 16, 0, 0);
}

// ---------------------------------------------------------------------------
// Kernel 0: weights -> MFMA B-fragment order + f32 bias.
// ---------------------------------------------------------------------------
__global__ void k_prep(const float* __restrict__ Wq, const float* __restrict__ bq,
                       const float* __restrict__ Wk, const float* __restrict__ bk,
                       const float* __restrict__ Wv, const float* __restrict__ bv,
                       u16* __restrict__ wtf, float* __restrict__ bias) {
  const int f = blockIdx.x;        // 0..159 = ct*8+ks
  const int L = threadIdx.x;       // 0..63
  const int ct = f >> 3, ks = f & 7;
  const int o = ct * 16 + (L & 15);
  const int ch = ks * 32 + (L >> 4) * 8;
  short8 v8;
#pragma unroll
  for (int jj = 0; jj < 8; jj++) {
    const int c = ch + jj;
    float v;
    if (o < 32)       v = Wq[c * CQK + o];
    else if (o < 64)  v = Wk[c * CQK + (o - 32)];
    else              v = Wv[c * CDIM + (o - 64)];
    v8[jj] = (short)f2bf(v);
  }
  *(short8*)(wtf + (size_t)f * 512 + L * 8) = v8;
  if (f == 0) {
    for (int i = L; i < 320; i += 64) {
      if (i < 32)      bias[i] = bq[i];
      else if (i < 64) bias[i] = bk[i - 32];
      else             bias[i] = bv[i - 64];
    }
  }
}

// ---------------------------------------------------------------------------
// Kernel 1: fused cvt+proj. K outputs pre-scaled by log2(e) (exp2 trick).
// V^T stored with intra-16B half-swap on rows with (c>>3)&1 == 1 (matches the
// P-LDS half swizzle in k_attn so PV's A/B k-orders stay aligned).
//
// Wave->work mapping: wave w owns ALL 64 rows x 5 ct-columns (ct = j*4 + w),
// so each weight fragment is loaded from global ONCE per block (160 KB/block
// vs 640 KB/block for the old rows-split mapping), held in registers, and
// reused across 4 row-groups (20 MFMA per 5 loads). ks-loop is barrier-free;
// wfA/wfB double-buffer + pre-sync ks=0 prefetch keep loads under MFMAs.
// ct = j*4 + w makes epilogues line up: j=0 -> wave w = q/k column block w;
// j=cg+1 -> wave w plays old t4=w role, preserving the V^T layout exactly.
// ---------------------------------------------------------------------------
__global__ __launch_bounds__(256, 2) void k_proj(
    const float* __restrict__ x, const u16* __restrict__ wtf,
    const float* __restrict__ bias,
    u16* __restrict__ q_ws, u16* __restrict__ k_ws, u16* __restrict__ vt_ws) {
  __shared__ u16 x_lds[64 * 264];
  __shared__ u16 vt_t[64 * 72];
  const int m0 = blockIdx.x * 64;
  const int tid = threadIdx.x;
  const int w = tid >> 6, L = tid & 63;
  const int lr = L & 15, q4 = L >> 4;

  // ks=0 weight prefetch (independent of LDS) — flies across the x staging.
  short8 wfA[5], wfB[5];
#pragma unroll
  for (int j = 0; j < 5; j++)
    wfA[j] = *(const short8*)(wtf + ((size_t)((j * 4 + w) * 8 + 0)) * 512 + L * 8);

  // stage + convert x tile via perm-packs
#pragma unroll
  for (int ii = 0; ii < 8; ii++) {
    const int e = (tid + 256 * ii) * 8;
    const int row = e >> 8, col = e & 255;
    const float* src = x + (size_t)(m0 + row) * CDIM + col;
    f32x4 a = *(const f32x4*)src;
    f32x4 b4 = *(const f32x4*)(src + 4);
    u32x4 pk;
    pk[0] = pack2(a[0], a[1]);
    pk[1] = pack2(a[2], a[3]);
    pk[2] = pack2(b4[0], b4[1]);
    pk[3] = pack2(b4[2], b4[3]);
    *(u32x4*)&x_lds[row * 264 + col] = pk;
  }
  __syncthreads();

  f32x4 acc[4][5];
#pragma unroll
  for (int rg = 0; rg < 4; rg++)
#pragma unroll
    for (int j = 0; j < 5; j++) acc[rg][j] = (f32x4){0.f, 0.f, 0.f, 0.f};

#pragma unroll
  for (int ks = 0; ks < 8; ks++) {
    // prefetch next ks-slice into the other buffer (no barriers in this loop)
    if (ks < 7) {
#pragma unroll
      for (int j = 0; j < 5; j++) {
        short8 v = *(const short8*)(wtf +
            ((size_t)((j * 4 + w) * 8 + ks + 1)) * 512 + L * 8);
        if (ks & 1) wfA[j] = v; else wfB[j] = v;
      }
    }
#pragma unroll
    for (int rg = 0; rg < 4; rg++) {
      short8 a = *(const short8*)&x_lds[(rg * 16 + lr) * 264 + ks * 32 + q4 * 8];
#pragma unroll
      for (int j = 0; j < 5; j++)
        acc[rg][j] = MFMA16(a, (ks & 1) ? wfB[j] : wfA[j], acc[rg][j]);
    }
  }

  // q/k epilogue (j=0 -> ct = w; k scaled by log2e). Branch is wave-uniform.
  {
    const float bb = bias[w * 16 + lr];
#pragma unroll
    for (int rg = 0; rg < 4; rg++)
#pragma unroll
      for (int r = 0; r < 4; r++) {
        const int row = m0 + rg * 16 + q4 * 4 + r;
        float v = acc[rg][0][r] + bb;
        if (w < 2) q_ws[(size_t)row * CQK + w * 16 + lr] = f2bf(v);
        else       k_ws[(size_t)row * CQK + (w - 2) * 16 + lr] = f2bf(v * LOG2E);
      }
  }
  // v epilogue: transpose via LDS with half-swap, b64 packed writes.
  // Per cg, wave w contributes ct = 4 + cg*4 + w (old t4 == w), channels
  // c_l = w*16+lr, all 64 rows via rg. Physical layout identical to before.
  const int b = m0 >> 12, nloc = m0 & 4095;
  const int rb2 = ((lr >> 3) & 1) << 2;       // row-bit3 of c_l = w*16+lr
  const int c_l = w * 16 + lr;
#pragma unroll
  for (int cg = 0; cg < 4; cg++) {
    __syncthreads();
    const int j = cg + 1;
    const float bb = bias[(4 + cg * 4 + w) * 16 + lr];
#pragma unroll
    for (int rg = 0; rg < 4; rg++) {
      const int n_base = (rg * 16 + q4 * 4) ^ rb2;  // half-swapped physical pos
      u32x2 pk;
      pk[0] = pack2(acc[rg][j][0] + bb, acc[rg][j][1] + bb);
      pk[1] = pack2(acc[rg][j][2] + bb, acc[rg][j][3] + bb);
      *(u32x2*)&vt_t[c_l * 72 + n_base] = pk;
    }
    __syncthreads();
#pragma unroll
    for (int i = 0; i < 2; i++) {
      const int gch = tid + 256 * i;
      const int cl2 = gch >> 3, jc = gch & 7;
      short8 v = *(const short8*)&vt_t[cl2 * 72 + jc * 8];
      *(short8*)(vt_ws + ((size_t)(b * CDIM + cg * 64 + cl2)) * NTOK + nloc + jc * 8) = v;
    }
  }
}

// ---------------------------------------------------------------------------
// Kernel 2: flash attention. S^T MFMA -> b64 P writes (chunk XOR + half-swap
// swizzle: conflict-free write phases). Shared P + 32x32x16 PV. V^T DMA
// double-buffer; Q double-buffered in registers one tile ahead; DMA issued
// after the PV gate so vmcnt(0) is cheap and needs no manual counting.
// ---------------------------------------------------------------------------
__global__ __launch_bounds__(256, 4) void k_attn(
    const float* __restrict__ x, const u16* __restrict__ q_ws,
    const u16* __restrict__ k_ws, const u16* __restrict__ vt_ws,
    const float* __restrict__ gamma, float* __restrict__ out) {
  __shared__ u16 vt_lds[2][128 * 64];
  __shared__ u16 p_lds[64 * 64];

  const int bid = blockIdx.x;
  const int b = bid & 7;
  const int chalf = (bid >> 3) & 1;
  const int it = bid >> 4;
  const int i0 = it * 64;
  const int c0 = chalf * 128;
  const int tid = threadIdx.x;
  const int w = tid >> 6, L = tid & 63;
  const int lr = L & 15, q4 = L >> 4;
  const int L31 = L & 31, Lhi = L >> 5, L7 = L & 7;
  const int ih = w & 1, cpair = w >> 1;

  const short8 a_k = *(const short8*)(k_ws +
      ((size_t)(b * NTOK + i0 + w * 16 + lr)) * CQK + q4 * 8);

  const int cl_base = tid >> 3;
  const int jc_sw = (tid & 7) ^ (cl_base & 7);
  const u16* vt_g = vt_ws + ((size_t)(b * CDIM + c0 + cl_base)) * NTOK + jc_sw * 8;
  const u16* q_base = q_ws + (size_t)b * NTOK * CQK;

  f32x16 o_acc[2];
#pragma unroll
  for (int t = 0; t < 2; t++)
#pragma unroll
    for (int e = 0; e < 16; e++) o_acc[t][e] = 0.f;
  float lsum = 0.f;

  // P write base: row i = w*16+lr; half = (q4&1) ^ ((i>>3)&1) (phase-spreads
  // the b64 writes across all 32 banks); chunk XOR with lr&7 as before.
  u16* pw0 = p_lds + (w * 16 + lr) * 64 + (((q4 & 1) ^ ((lr >> 3) & 1)) << 2);
  const int q4h = q4 >> 1;

  // prologue: Q tile 0 -> regs; DMA tile 0 -> buf 0
  short8 bqA[4], bqB[4];
#pragma unroll
  for (int t = 0; t < 4; t++)
    bqA[t] = *(const short8*)(q_base + (size_t)(t * 16 + lr) * CQK + q4 * 8);
#pragma unroll
  for (int ii = 0; ii < 4; ii++)
    gl_lds16(vt_g + (size_t)(ii * 32) * NTOK, &vt_lds[0][ii * 2048 + w * 512]);

#define ATTN_ITER(JT, VB_CUR, VB_NXT, BQ, BQN)                                   \
  do {                                                                           \
    const int j0 = (JT) * 64;                                                    \
    BAR_LDS(); /* prev PV reads of p_lds & VB_NXT done */                        \
    /* Q prefetch for next tile (past-end reads land in k_ws: safe, unused) */   \
    _Pragma("unroll")                                                            \
    for (int t = 0; t < 4; t++)                                                  \
      BQN[t] = *(const short8*)(q_base +                                         \
               (size_t)(j0 + 64 + t * 16 + lr) * CQK + q4 * 8);                  \
    /* S^T = Q.K^T (current Q regs: already resident, zero wait) */              \
    f32x4 s[4];                                                                  \
    _Pragma("unroll")                                                            \
    for (int t = 0; t < 4; t++)                                                  \
      s[t] = MFMA16(BQ[t], a_k, ((f32x4){0.f, 0.f, 0.f, 0.f}));                  \
    /* P = exp2(S) (K pre-scaled by log2e); b64 swizzled writes */               \
    _Pragma("unroll")                                                            \
    for (int t = 0; t < 4; t++) {                                                \
      const float p0 = fexp2(s[t][0]);                                           \
      const float p1 = fexp2(s[t][1]);                                           \
      const float p2 = fexp2(s[t][2]);                                           \
      const float p3 = fexp2(s[t][3]);                                           \
      lsum += (p0 + p1) + (p2 + p3);                                             \
      u32x2 pk;                                                                  \
      pk[0] = pack2(p0, p1);                                                     \
      pk[1] = pack2(p2, p3);                                                     \
      *(u32x2*)(pw0 + (((2 * t + q4h) ^ (lr & 7)) * 8)) = pk;                    \
    }                                                                            \
    BAR_VMEM(); /* DMA(JT) landed (issued a full iter ago); P visible */         \
    /* DMA next tile now: flies across PV + next iter's S/exp phases */          \
    if ((JT) < 63) {                                                             \
      _Pragma("unroll")                                                          \
      for (int ii = 0; ii < 4; ii++)                                             \
        gl_lds16(vt_g + (size_t)(ii * 32) * NTOK + (j0 + 64),                    \
                 &VB_NXT[ii * 2048 + w * 512]);                                  \
    }                                                                            \
    /* O += P*V (32x32x16; A/B k-orders both half-swapped by row bit3) */        \
    _Pragma("unroll")                                                            \
    for (int ks = 0; ks < 4; ks++) {                                             \
      const int slot = (((ks * 2 + Lhi) ^ L7)) * 8;                              \
      short8 a_p = *(const short8*)(p_lds + (ih * 32 + L31) * 64 + slot);        \
      _Pragma("unroll")                                                          \
      for (int ct2 = 0; ct2 < 2; ct2++) {                                        \
        const int cl = (cpair * 2 + ct2) * 32 + L31;                             \
        short8 b_v = *(const short8*)(&VB_CUR[0] + cl * 64 + slot);              \
        o_acc[ct2] = MFMA32(a_p, b_v, o_acc[ct2]);                               \
      }                                                                          \
    }                                                                            \
  } while (0)

  for (int jt2 = 0; jt2 < 64; jt2 += 2) {
    ATTN_ITER(jt2,     vt_lds[0], vt_lds[1], bqA, bqB);
    ATTN_ITER(jt2 + 1, vt_lds[1], vt_lds[0], bqB, bqA);
  }
#undef ATTN_ITER

  // softmax denominators
  float s2 = lsum;
  s2 += __shfl_xor(s2, 16);
  s2 += __shfl_xor(s2, 32);
  const float rl = 1.0f / s2;
  BAR_LDS();
  float* lp = (float*)p_lds;
  if (q4 == 0) lp[w * 16 + lr] = rl;
  BAR_LDS();

  float linv[16];
#pragma unroll
  for (int rg = 0; rg < 16; rg++)
    linv[rg] = lp[ih * 32 + (rg & 3) + 8 * (rg >> 2) + 4 * Lhi];

  const float g = gamma[0];
#pragma unroll
  for (int ct2 = 0; ct2 < 2; ct2++) {
    const int c = c0 + (cpair * 2 + ct2) * 32 + L31;
#pragma unroll
    for (int rg = 0; rg < 16; rg++) {
      const int i = i0 + ih * 32 + (rg & 3) + 8 * (rg >> 2) + 4 * Lhi;
      const size_t idx = ((size_t)(b * NTOK + i)) * CDIM + c;
      out[idx] = g * (o_acc[ct2][rg] * linv[rg]) + x[idx];
    }
  }
}

// ---------------------------------------------------------------------------
extern "C" void kernel_launch(void* const* d_in, const int* in_sizes, int n_in,
                              void* d_out, int out_size, void* d_ws, size_t ws_size,
                              hipStream_t stream) {
  const float* x  = (const float*)d_in[0];
  const float* Wq = (const float*)d_in[1];
  const float* bq = (const float*)d_in[2];
  const float* Wk = (const float*)d_in[3];
  const float* bk = (const float*)d_in[4];
  const float* Wv = (const float*)d_in[5];
  const float* bv = (const float*)d_in[6];
  const float* gamma = (const float*)d_in[7];
  float* out = (float*)d_out;

  char* ws = (char*)d_ws;
  u16* q_ws  = (u16*)(ws);
  u16* k_ws  = (u16*)(ws + (2u << 20));
  u16* vt_ws = (u16*)(ws + (4u << 20));
  u16* wtf   = (u16*)(ws + (20u << 20));
  float* bias = (float*)(ws + (20u << 20) + (256u << 10));

  k_prep<<<160, 64, 0, stream>>>(Wq, bq, Wk, bk, Wv, bv, wtf, bias);
  k_proj<<<512, 256, 0, stream>>>(x, wtf, bias, q_ws, k_ws, vt_ws);
  k_attn<<<1024, 256, 0, stream>>>(x, q_ws, k_ws, vt_ws, gamma, out);
}

// Round 3
// 196.825 us; speedup vs baseline: 1.1245x; 1.0877x over previous
//
#include <hip/hip_runtime.h>

typedef __attribute__((ext_vector_type(8))) short short8;
typedef __attribute__((ext_vector_type(4))) float f32x4;
typedef __attribute__((ext_vector_type(16))) float f32x16;
typedef __attribute__((ext_vector_type(2))) unsigned int u32x2;
typedef __attribute__((ext_vector_type(4))) unsigned int u32x4;
typedef unsigned short u16;
typedef unsigned int u32;

#define MFMA16(a, b, c) __builtin_amdgcn_mfma_f32_16x16x32_bf16((a), (b), (c), 0, 0, 0)
#define MFMA32(a, b, c) __builtin_amdgcn_mfma_f32_32x32x16_bf16((a), (b), (c), 0, 0, 0)

// barrier flavors: BAR_VMEM drains the async DMA (+P visibility); BAR_LDS is
// LDS-only so global prefetches stay in flight across it.
#define BAR_VMEM() asm volatile("s_waitcnt vmcnt(0) lgkmcnt(0)\ns_barrier" ::: "memory")
#define BAR_LDS()  asm volatile("s_waitcnt lgkmcnt(0)\ns_barrier" ::: "memory")

#define BATCH 8
#define NTOK 4096
#define CDIM 256
#define CQK 32
#define LOG2E 1.4426950408889634f

__device__ __forceinline__ u16 f2bf(float f) {
  u32 u = __float_as_uint(f);
  return (u16)((u + 0x7FFFu + ((u >> 16) & 1u)) >> 16);
}
// pack two f32 -> two bf16 (round-half-up) in one u32: bf(a) | bf(b)<<16
__device__ __forceinline__ u32 pack2(float a, float b) {
  const u32 ua = __float_as_uint(a) + 0x8000u;
  const u32 ub = __float_as_uint(b) + 0x8000u;
#if __has_builtin(__builtin_amdgcn_perm)
  return __builtin_amdgcn_perm(ub, ua, 0x07060302u);  // {ua.b2,ua.b3,ub.b2,ub.b3}
#else
  return (ua >> 16) | (ub & 0xFFFF0000u);
#endif
}
__device__ __forceinline__ float fexp2(float x) {
#if __has_builtin(__builtin_amdgcn_exp2f)
  return __builtin_amdgcn_exp2f(x);
#else
  return exp2f(x);
#endif
}
__device__ __forceinline__ void gl_lds16(const u16* g, u16* l) {
  __builtin_amdgcn_global_load_lds(
      (const __attribute__((address_space(1))) unsigned int*)(g),
      (__attribute__((address_space(3))) unsigned int*)(l), 16, 0, 0);
}

// ---------------------------------------------------------------------------
// Kernel 0: weights -> MFMA B-fragment order + f32 bias.
// ---------------------------------------------------------------------------
__global__ void k_prep(const float* __restrict__ Wq, const float* __restrict__ bq,
                       const float* __restrict__ Wk, const float* __restrict__ bk,
                       const float* __restrict__ Wv, const float* __restrict__ bv,
                       u16* __restrict__ wtf, float* __restrict__ bias) {
  const int f = blockIdx.x;        // 0..159 = ct*8+ks
  const int L = threadIdx.x;       // 0..63
  const int ct = f >> 3, ks = f & 7;
  const int o = ct * 16 + (L & 15);
  const int ch = ks * 32 + (L >> 4) * 8;
  short8 v8;
#pragma unroll
  for (int jj = 0; jj < 8; jj++) {
    const int c = ch + jj;
    float v;
    if (o < 32)       v = Wq[c * CQK + o];
    else if (o < 64)  v = Wk[c * CQK + (o - 32)];
    else              v = Wv[c * CDIM + (o - 64)];
    v8[jj] = (short)f2bf(v);
  }
  *(short8*)(wtf + (size_t)f * 512 + L * 8) = v8;
  if (f == 0) {
    for (int i = L; i < 320; i += 64) {
      if (i < 32)      bias[i] = bq[i];
      else if (i < 64) bias[i] = bk[i - 32];
      else             bias[i] = bv[i - 64];
    }
  }
}

// ---------------------------------------------------------------------------
// Kernel 1: fused cvt+proj. K outputs pre-scaled by log2(e) (exp2 trick).
// V^T stored with intra-16B half-swap on rows with (c>>3)&1 == 1 (matches the
// P-LDS half swizzle in k_attn so PV's A/B k-orders stay aligned).
//
// Wave->work mapping: wave w owns ALL 64 rows x 5 ct-columns (ct = j*4 + w),
// so each weight fragment is loaded from global ONCE per block, held in
// registers, and reused across 4 row-groups (20 MFMA per 5 loads).
// ---------------------------------------------------------------------------
__global__ __launch_bounds__(256, 2) void k_proj(
    const float* __restrict__ x, const u16* __restrict__ wtf,
    const float* __restrict__ bias,
    u16* __restrict__ q_ws, u16* __restrict__ k_ws, u16* __restrict__ vt_ws) {
  __shared__ u16 x_lds[64 * 264];
  __shared__ u16 vt_t[64 * 72];
  const int m0 = blockIdx.x * 64;
  const int tid = threadIdx.x;
  const int w = tid >> 6, L = tid & 63;
  const int lr = L & 15, q4 = L >> 4;

  // ks=0 weight prefetch (independent of LDS) — flies across the x staging.
  short8 wfA[5], wfB[5];
#pragma unroll
  for (int j = 0; j < 5; j++)
    wfA[j] = *(const short8*)(wtf + ((size_t)((j * 4 + w) * 8 + 0)) * 512 + L * 8);

  // stage + convert x tile via perm-packs
#pragma unroll
  for (int ii = 0; ii < 8; ii++) {
    const int e = (tid + 256 * ii) * 8;
    const int row = e >> 8, col = e & 255;
    const float* src = x + (size_t)(m0 + row) * CDIM + col;
    f32x4 a = *(const f32x4*)src;
    f32x4 b4 = *(const f32x4*)(src + 4);
    u32x4 pk;
    pk[0] = pack2(a[0], a[1]);
    pk[1] = pack2(a[2], a[3]);
    pk[2] = pack2(b4[0], b4[1]);
    pk[3] = pack2(b4[2], b4[3]);
    *(u32x4*)&x_lds[row * 264 + col] = pk;
  }
  __syncthreads();

  f32x4 acc[4][5];
#pragma unroll
  for (int rg = 0; rg < 4; rg++)
#pragma unroll
    for (int j = 0; j < 5; j++) acc[rg][j] = (f32x4){0.f, 0.f, 0.f, 0.f};

#pragma unroll
  for (int ks = 0; ks < 8; ks++) {
    // prefetch next ks-slice into the other buffer (no barriers in this loop)
    if (ks < 7) {
#pragma unroll
      for (int j = 0; j < 5; j++) {
        short8 v = *(const short8*)(wtf +
            ((size_t)((j * 4 + w) * 8 + ks + 1)) * 512 + L * 8);
        if (ks & 1) wfA[j] = v; else wfB[j] = v;
      }
    }
#pragma unroll
    for (int rg = 0; rg < 4; rg++) {
      short8 a = *(const short8*)&x_lds[(rg * 16 + lr) * 264 + ks * 32 + q4 * 8];
#pragma unroll
      for (int j = 0; j < 5; j++)
        acc[rg][j] = MFMA16(a, (ks & 1) ? wfB[j] : wfA[j], acc[rg][j]);
    }
  }

  // q/k epilogue (j=0 -> ct = w; k scaled by log2e). Branch is wave-uniform.
  {
    const float bb = bias[w * 16 + lr];
#pragma unroll
    for (int rg = 0; rg < 4; rg++)
#pragma unroll
      for (int r = 0; r < 4; r++) {
        const int row = m0 + rg * 16 + q4 * 4 + r;
        float v = acc[rg][0][r] + bb;
        if (w < 2) q_ws[(size_t)row * CQK + w * 16 + lr] = f2bf(v);
        else       k_ws[(size_t)row * CQK + (w - 2) * 16 + lr] = f2bf(v * LOG2E);
      }
  }
  // v epilogue: transpose via LDS with half-swap, b64 packed writes.
  const int b = m0 >> 12, nloc = m0 & 4095;
  const int rb2 = ((lr >> 3) & 1) << 2;       // row-bit3 of c_l = w*16+lr
  const int c_l = w * 16 + lr;
#pragma unroll
  for (int cg = 0; cg < 4; cg++) {
    __syncthreads();
    const int j = cg + 1;
    const float bb = bias[(4 + cg * 4 + w) * 16 + lr];
#pragma unroll
    for (int rg = 0; rg < 4; rg++) {
      const int n_base = (rg * 16 + q4 * 4) ^ rb2;  // half-swapped physical pos
      u32x2 pk;
      pk[0] = pack2(acc[rg][j][0] + bb, acc[rg][j][1] + bb);
      pk[1] = pack2(acc[rg][j][2] + bb, acc[rg][j][3] + bb);
      *(u32x2*)&vt_t[c_l * 72 + n_base] = pk;
    }
    __syncthreads();
#pragma unroll
    for (int i = 0; i < 2; i++) {
      const int gch = tid + 256 * i;
      const int cl2 = gch >> 3, jc = gch & 7;
      short8 v = *(const short8*)&vt_t[cl2 * 72 + jc * 8];
      *(short8*)(vt_ws + ((size_t)(b * CDIM + cg * 64 + cl2)) * NTOK + nloc + jc * 8) = v;
    }
  }
}

// ---------------------------------------------------------------------------
// Kernel 2: flash attention, chalf-MERGED: one block = 64 i-rows x ALL 256
// channels (grid 512). S^T/exp/softmax/P-writes happen once (the old split
// duplicated them per channel-half). Wave w owns 64 rows x 64 channels
// (2 ih x 2 ct2 32x32 tiles), so every a_p/b_v b128 read feeds 2 MFMA32:
// 1.0 LDS-reads/MFMA vs 1.5 before — k_attn was LDS-pipe-bound.
// Q-prefetch is issued AFTER the BAR_VMEM drain (next to the V DMA) so
// vmcnt(0) never waits on a freshly-issued Q load.
// ---------------------------------------------------------------------------
__global__ __launch_bounds__(256, 2) void k_attn(
    const float* __restrict__ x, const u16* __restrict__ q_ws,
    const u16* __restrict__ k_ws, const u16* __restrict__ vt_ws,
    const float* __restrict__ gamma, float* __restrict__ out) {
  __shared__ u16 vt_lds[2][256 * 64];   // 64 KB: dbuf x (256 ch x 64 j)
  __shared__ u16 p_lds[64 * 64];        // 8 KB

  const int bid = blockIdx.x;
  const int b = bid & 7;                // same-b blocks land on one XCD
  const int it = bid >> 3;
  const int i0 = it * 64;
  const int tid = threadIdx.x;
  const int w = tid >> 6, L = tid & 63;
  const int lr = L & 15, q4 = L >> 4;
  const int L31 = L & 31, Lhi = L >> 5, L7 = L & 7;

  const short8 a_k = *(const short8*)(k_ws +
      ((size_t)(b * NTOK + i0 + w * 16 + lr)) * CQK + q4 * 8);

  const int cl_base = tid >> 3;                       // 0..31
  const int jc_sw = (tid & 7) ^ (cl_base & 7);        // pre-swizzled global j
  const u16* vt_g = vt_ws + ((size_t)(b * CDIM + cl_base)) * NTOK + jc_sw * 8;
  const u16* q_base = q_ws + (size_t)b * NTOK * CQK;

  f32x16 o_acc[2][2];
#pragma unroll
  for (int ih = 0; ih < 2; ih++)
#pragma unroll
    for (int ct2 = 0; ct2 < 2; ct2++)
#pragma unroll
      for (int e = 0; e < 16; e++) o_acc[ih][ct2][e] = 0.f;
  float lsum = 0.f;

  // P write base: row i = w*16+lr; half = (q4&1) ^ ((i>>3)&1) (phase-spreads
  // the b64 writes across all 32 banks); chunk XOR with lr&7 as before.
  u16* pw0 = p_lds + (w * 16 + lr) * 64 + (((q4 & 1) ^ ((lr >> 3) & 1)) << 2);
  const int q4h = q4 >> 1;

  // prologue: Q tile 0 -> regs; DMA V tile 0 (all 256 ch) -> buf 0
  short8 bqA[4], bqB[4];
#pragma unroll
  for (int t = 0; t < 4; t++)
    bqA[t] = *(const short8*)(q_base + (size_t)(t * 16 + lr) * CQK + q4 * 8);
#pragma unroll
  for (int ii = 0; ii < 8; ii++)
    gl_lds16(vt_g + (size_t)(ii * 32) * NTOK, &vt_lds[0][ii * 2048 + w * 512]);

#define ATTN_ITER(JT, VB_CUR, VB_NXT, BQ, BQN)                                   \
  do {                                                                           \
    const int j0 = (JT) * 64;                                                    \
    BAR_LDS(); /* prev PV reads of p_lds & VB_NXT done */                        \
    /* S^T = Q.K^T (current Q regs: already resident) */                         \
    f32x4 s[4];                                                                  \
    _Pragma("unroll")                                                            \
    for (int t = 0; t < 4; t++)                                                  \
      s[t] = MFMA16(BQ[t], a_k, ((f32x4){0.f, 0.f, 0.f, 0.f}));                  \
    /* P = exp2(S) (K pre-scaled by log2e); b64 swizzled writes */               \
    _Pragma("unroll")                                                            \
    for (int t = 0; t < 4; t++) {                                                \
      const float p0 = fexp2(s[t][0]);                                           \
      const float p1 = fexp2(s[t][1]);                                           \
      const float p2 = fexp2(s[t][2]);                                           \
      const float p3 = fexp2(s[t][3]);                                           \
      lsum += (p0 + p1) + (p2 + p3);                                             \
      u32x2 pk;                                                                  \
      pk[0] = pack2(p0, p1);                                                     \
      pk[1] = pack2(p2, p3);                                                     \
      *(u32x2*)(pw0 + (((2 * t + q4h) ^ (lr & 7)) * 8)) = pk;                    \
    }                                                                            \
    BAR_VMEM(); /* DMA(JT) landed (issued a full iter ago); P visible */         \
    /* DMA next V tile + Q prefetch: both have a full PV+S+exp to fly */         \
    if ((JT) < 63) {                                                             \
      _Pragma("unroll")                                                          \
      for (int ii = 0; ii < 8; ii++)                                             \
        gl_lds16(vt_g + (size_t)(ii * 32) * NTOK + (j0 + 64),                    \
                 &VB_NXT[ii * 2048 + w * 512]);                                  \
    }                                                                            \
    _Pragma("unroll")                                                            \
    for (int t = 0; t < 4; t++)                                                  \
      BQN[t] = *(const short8*)(q_base +                                         \
               (size_t)(j0 + 64 + t * 16 + lr) * CQK + q4 * 8);                  \
    /* O += P*V: 2 ih x 2 ct2 tiles; each a_p/b_v read feeds 2 MFMA32 */         \
    _Pragma("unroll")                                                            \
    for (int ks = 0; ks < 4; ks++) {                                             \
      const int slot = (((ks * 2 + Lhi) ^ L7)) * 8;                              \
      short8 a_p0 = *(const short8*)(p_lds + L31 * 64 + slot);                   \
      short8 a_p1 = *(const short8*)(p_lds + (32 + L31) * 64 + slot);            \
      _Pragma("unroll")                                                          \
      for (int ct2 = 0; ct2 < 2; ct2++) {                                        \
        const int cl = w * 64 + ct2 * 32 + L31;                                  \
        short8 b_v = *(const short8*)(VB_CUR + cl * 64 + slot);                  \
        o_acc[0][ct2] = MFMA32(a_p0, b_v, o_acc[0][ct2]);                        \
        o_acc[1][ct2] = MFMA32(a_p1, b_v, o_acc[1][ct2]);                        \
      }                                                                          \
    }                                                                            \
  } while (0)

  for (int jt2 = 0; jt2 < 64; jt2 += 2) {
    ATTN_ITER(jt2,     vt_lds[0], vt_lds[1], bqA, bqB);
    ATTN_ITER(jt2 + 1, vt_lds[1], vt_lds[0], bqB, bqA);
  }
#undef ATTN_ITER

  // softmax denominators (one i-row per lane; sum across q4 groups)
  float s2 = lsum;
  s2 += __shfl_xor(s2, 16);
  s2 += __shfl_xor(s2, 32);
  const float rl = 1.0f / s2;
  BAR_LDS();
  float* lp = (float*)p_lds;
  if (q4 == 0) lp[w * 16 + lr] = rl;
  BAR_LDS();

  float linv2[2][16];
#pragma unroll
  for (int ih = 0; ih < 2; ih++)
#pragma unroll
    for (int rg = 0; rg < 16; rg++)
      linv2[ih][rg] = lp[ih * 32 + (rg & 3) + 8 * (rg >> 2) + 4 * Lhi];

  const float g = gamma[0];
#pragma unroll
  for (int ih = 0; ih < 2; ih++)
#pragma unroll
    for (int ct2 = 0; ct2 < 2; ct2++) {
      const int c = w * 64 + ct2 * 32 + L31;
#pragma unroll
      for (int rg = 0; rg < 16; rg++) {
        const int i = i0 + ih * 32 + (rg & 3) + 8 * (rg >> 2) + 4 * Lhi;
        const size_t idx = ((size_t)(b * NTOK + i)) * CDIM + c;
        out[idx] = g * (o_acc[ih][ct2][rg] * linv2[ih][rg]) + x[idx];
      }
    }
}

// ---------------------------------------------------------------------------
extern "C" void kernel_launch(void* const* d_in, const int* in_sizes, int n_in,
                              void* d_out, int out_size, void* d_ws, size_t ws_size,
                              hipStream_t stream) {
  const float* x  = (const float*)d_in[0];
  const float* Wq = (const float*)d_in[1];
  const float* bq = (const float*)d_in[2];
  const float* Wk = (const float*)d_in[3];
  const float* bk = (const float*)d_in[4];
  const float* Wv = (const float*)d_in[5];
  const float* bv = (const float*)d_in[6];
  const float* gamma = (const float*)d_in[7];
  float* out = (float*)d_out;

  char* ws = (char*)d_ws;
  u16* q_ws  = (u16*)(ws);
  u16* k_ws  = (u16*)(ws + (2u << 20));
  u16* vt_ws = (u16*)(ws + (4u << 20));
  u16* wtf   = (u16*)(ws + (20u << 20));
  float* bias = (float*)(ws + (20u << 20) + (256u << 10));

  k_prep<<<160, 64, 0, stream>>>(Wq, bq, Wk, bk, Wv, bv, wtf, bias);
  k_proj<<<512, 256, 0, stream>>>(x, wtf, bias, q_ws, k_ws, vt_ws);
  k_attn<<<512, 256, 0, stream>>>(x, q_ws, k_ws, vt_ws, gamma, out);
}

// Round 4
// 195.340 us; speedup vs baseline: 1.1330x; 1.0076x over previous
//
#include <hip/hip_runtime.h>

typedef __attribute__((ext_vector_type(8))) short short8;
typedef __attribute__((ext_vector_type(4))) float f32x4;
typedef __attribute__((ext_vector_type(16))) float f32x16;
typedef __attribute__((ext_vector_type(2))) unsigned int u32x2;
typedef __attribute__((ext_vector_type(4))) unsigned int u32x4;
typedef unsigned short u16;
typedef unsigned int u32;

#define MFMA16(a, b, c) __builtin_amdgcn_mfma_f32_16x16x32_bf16((a), (b), (c), 0, 0, 0)
#define MFMA32(a, b, c) __builtin_amdgcn_mfma_f32_32x32x16_bf16((a), (b), (c), 0, 0, 0)

// single barrier flavor used in the hot loop: drains async DMA + LDS ops.
#define BAR_VMEM() asm volatile("s_waitcnt vmcnt(0) lgkmcnt(0)\ns_barrier" ::: "memory")
#define BAR_LDS()  asm volatile("s_waitcnt lgkmcnt(0)\ns_barrier" ::: "memory")

#define BATCH 8
#define NTOK 4096
#define CDIM 256
#define CQK 32
#define LOG2E 1.4426950408889634f

__device__ __forceinline__ u16 f2bf(float f) {
  u32 u = __float_as_uint(f);
  return (u16)((u + 0x7FFFu + ((u >> 16) & 1u)) >> 16);
}
// pack two f32 -> two bf16 (round-half-up) in one u32: bf(a) | bf(b)<<16
__device__ __forceinline__ u32 pack2(float a, float b) {
  const u32 ua = __float_as_uint(a) + 0x8000u;
  const u32 ub = __float_as_uint(b) + 0x8000u;
#if __has_builtin(__builtin_amdgcn_perm)
  return __builtin_amdgcn_perm(ub, ua, 0x07060302u);  // {ua.b2,ua.b3,ub.b2,ub.b3}
#else
  return (ua >> 16) | (ub & 0xFFFF0000u);
#endif
}
__device__ __forceinline__ float fexp2(float x) {
#if __has_builtin(__builtin_amdgcn_exp2f)
  return __builtin_amdgcn_exp2f(x);
#else
  return exp2f(x);
#endif
}
__device__ __forceinline__ void gl_lds16(const u16* g, u16* l) {
  __builtin_amdgcn_global_load_lds(
      (const __attribute__((address_space(1))) unsigned int*)(g),
      (__attribute__((address_space(3))) unsigned int*)(l), 16, 0, 0);
}

// ---------------------------------------------------------------------------
// Kernel 0: weights -> MFMA B-fragment order + f32 bias.
// ---------------------------------------------------------------------------
__global__ void k_prep(const float* __restrict__ Wq, const float* __restrict__ bq,
                       const float* __restrict__ Wk, const float* __restrict__ bk,
                       const float* __restrict__ Wv, const float* __restrict__ bv,
                       u16* __restrict__ wtf, float* __restrict__ bias) {
  const int f = blockIdx.x;        // 0..159 = ct*8+ks
  const int L = threadIdx.x;       // 0..63
  const int ct = f >> 3, ks = f & 7;
  const int o = ct * 16 + (L & 15);
  const int ch = ks * 32 + (L >> 4) * 8;
  short8 v8;
#pragma unroll
  for (int jj = 0; jj < 8; jj++) {
    const int c = ch + jj;
    float v;
    if (o < 32)       v = Wq[c * CQK + o];
    else if (o < 64)  v = Wk[c * CQK + (o - 32)];
    else              v = Wv[c * CDIM + (o - 64)];
    v8[jj] = (short)f2bf(v);
  }
  *(short8*)(wtf + (size_t)f * 512 + L * 8) = v8;
  if (f == 0) {
    for (int i = L; i < 320; i += 64) {
      if (i < 32)      bias[i] = bq[i];
      else if (i < 64) bias[i] = bk[i - 32];
      else             bias[i] = bv[i - 64];
    }
  }
}

// ---------------------------------------------------------------------------
// Kernel 1: fused cvt+proj. K outputs pre-scaled by log2(e) (exp2 trick).
// V^T stored with intra-16B half-swap on rows with (c>>3)&1 == 1 (matches the
// P-LDS half swizzle in k_attn so PV's A/B k-orders stay aligned).
//
// Wave->work mapping: wave w owns ALL 64 rows x 5 ct-columns (ct = j*4 + w),
// so each weight fragment is loaded from global ONCE per block, held in
// registers, and reused across 4 row-groups (20 MFMA per 5 loads).
// ---------------------------------------------------------------------------
__global__ __launch_bounds__(256, 2) void k_proj(
    const float* __restrict__ x, const u16* __restrict__ wtf,
    const float* __restrict__ bias,
    u16* __restrict__ q_ws, u16* __restrict__ k_ws, u16* __restrict__ vt_ws) {
  __shared__ u16 x_lds[64 * 264];
  __shared__ u16 vt_t[64 * 72];
  const int m0 = blockIdx.x * 64;
  const int tid = threadIdx.x;
  const int w = tid >> 6, L = tid & 63;
  const int lr = L & 15, q4 = L >> 4;

  // ks=0 weight prefetch (independent of LDS) — flies across the x staging.
  short8 wfA[5], wfB[5];
#pragma unroll
  for (int j = 0; j < 5; j++)
    wfA[j] = *(const short8*)(wtf + ((size_t)((j * 4 + w) * 8 + 0)) * 512 + L * 8);

  // stage + convert x tile via perm-packs
#pragma unroll
  for (int ii = 0; ii < 8; ii++) {
    const int e = (tid + 256 * ii) * 8;
    const int row = e >> 8, col = e & 255;
    const float* src = x + (size_t)(m0 + row) * CDIM + col;
    f32x4 a = *(const f32x4*)src;
    f32x4 b4 = *(const f32x4*)(src + 4);
    u32x4 pk;
    pk[0] = pack2(a[0], a[1]);
    pk[1] = pack2(a[2], a[3]);
    pk[2] = pack2(b4[0], b4[1]);
    pk[3] = pack2(b4[2], b4[3]);
    *(u32x4*)&x_lds[row * 264 + col] = pk;
  }
  __syncthreads();

  f32x4 acc[4][5];
#pragma unroll
  for (int rg = 0; rg < 4; rg++)
#pragma unroll
    for (int j = 0; j < 5; j++) acc[rg][j] = (f32x4){0.f, 0.f, 0.f, 0.f};

#pragma unroll
  for (int ks = 0; ks < 8; ks++) {
    // prefetch next ks-slice into the other buffer (no barriers in this loop)
    if (ks < 7) {
#pragma unroll
      for (int j = 0; j < 5; j++) {
        short8 v = *(const short8*)(wtf +
            ((size_t)((j * 4 + w) * 8 + ks + 1)) * 512 + L * 8);
        if (ks & 1) wfA[j] = v; else wfB[j] = v;
      }
    }
#pragma unroll
    for (int rg = 0; rg < 4; rg++) {
      short8 a = *(const short8*)&x_lds[(rg * 16 + lr) * 264 + ks * 32 + q4 * 8];
#pragma unroll
      for (int j = 0; j < 5; j++)
        acc[rg][j] = MFMA16(a, (ks & 1) ? wfB[j] : wfA[j], acc[rg][j]);
    }
  }

  // q/k epilogue (j=0 -> ct = w; k scaled by log2e). Branch is wave-uniform.
  {
    const float bb = bias[w * 16 + lr];
#pragma unroll
    for (int rg = 0; rg < 4; rg++)
#pragma unroll
      for (int r = 0; r < 4; r++) {
        const int row = m0 + rg * 16 + q4 * 4 + r;
        float v = acc[rg][0][r] + bb;
        if (w < 2) q_ws[(size_t)row * CQK + w * 16 + lr] = f2bf(v);
        else       k_ws[(size_t)row * CQK + (w - 2) * 16 + lr] = f2bf(v * LOG2E);
      }
  }
  // v epilogue: transpose via LDS with half-swap, b64 packed writes.
  const int b = m0 >> 12, nloc = m0 & 4095;
  const int rb2 = ((lr >> 3) & 1) << 2;       // row-bit3 of c_l = w*16+lr
  const int c_l = w * 16 + lr;
#pragma unroll
  for (int cg = 0; cg < 4; cg++) {
    __syncthreads();
    const int j = cg + 1;
    const float bb = bias[(4 + cg * 4 + w) * 16 + lr];
#pragma unroll
    for (int rg = 0; rg < 4; rg++) {
      const int n_base = (rg * 16 + q4 * 4) ^ rb2;  // half-swapped physical pos
      u32x2 pk;
      pk[0] = pack2(acc[rg][j][0] + bb, acc[rg][j][1] + bb);
      pk[1] = pack2(acc[rg][j][2] + bb, acc[rg][j][3] + bb);
      *(u32x2*)&vt_t[c_l * 72 + n_base] = pk;
    }
    __syncthreads();
#pragma unroll
    for (int i = 0; i < 2; i++) {
      const int gch = tid + 256 * i;
      const int cl2 = gch >> 3, jc = gch & 7;
      short8 v = *(const short8*)&vt_t[cl2 * 72 + jc * 8];
      *(short8*)(vt_ws + ((size_t)(b * CDIM + cg * 64 + cl2)) * NTOK + nloc + jc * 8) = v;
    }
  }
}

// ---------------------------------------------------------------------------
// Kernel 2: flash attention, software-pipelined: ONE barrier per j-tile.
// p_lds double-buffered (2x8KB) so S^T(t+1)+exp+P-writes run concurrently
// with PV(t) inside the same barrier-free region — exp VALU rides under the
// 512-cyc MFMA32 pipe occupancy instead of serializing ahead of it.
// Race audit: P(t+1) writes target the p-buffer last read at PV(t-1) (top
// barrier orders); DMA(t+1) targets the vt-buffer last read at PV(t-1);
// everything else is intra-wave. Total LDS 80KB -> 2 blocks/CU (160KB pool).
// ---------------------------------------------------------------------------
__global__ __launch_bounds__(256, 2) void k_attn(
    const float* __restrict__ x, const u16* __restrict__ q_ws,
    const u16* __restrict__ k_ws, const u16* __restrict__ vt_ws,
    const float* __restrict__ gamma, float* __restrict__ out) {
  __shared__ u16 vt_lds[2][256 * 64];   // 64 KB: dbuf x (256 ch x 64 j)
  __shared__ u16 p_lds[2][64 * 64];     // 16 KB: dbuf P

  const int bid = blockIdx.x;
  const int b = bid & 7;                // same-b blocks land on one XCD
  const int it = bid >> 3;
  const int i0 = it * 64;
  const int tid = threadIdx.x;
  const int w = tid >> 6, L = tid & 63;
  const int lr = L & 15, q4 = L >> 4;
  const int L31 = L & 31, Lhi = L >> 5, L7 = L & 7;

  const short8 a_k = *(const short8*)(k_ws +
      ((size_t)(b * NTOK + i0 + w * 16 + lr)) * CQK + q4 * 8);

  const int cl_base = tid >> 3;                       // 0..31
  const int jc_sw = (tid & 7) ^ (cl_base & 7);        // pre-swizzled global j
  const u16* vt_g = vt_ws + ((size_t)(b * CDIM + cl_base)) * NTOK + jc_sw * 8;
  const u16* q_base = q_ws + (size_t)b * NTOK * CQK;

  f32x16 o_acc[2][2];
#pragma unroll
  for (int ih = 0; ih < 2; ih++)
#pragma unroll
    for (int ct2 = 0; ct2 < 2; ct2++)
#pragma unroll
      for (int e = 0; e < 16; e++) o_acc[ih][ct2][e] = 0.f;
  float lsum = 0.f;

  // P write base offset: row i = w*16+lr; half = (q4&1)^((i>>3)&1); chunk XOR.
  const int pw_off = (w * 16 + lr) * 64 + (((q4 & 1) ^ ((lr >> 3) & 1)) << 2);
  const int q4h = q4 >> 1;
  u16* const pl0 = &p_lds[0][0];
  u16* const pl1 = &p_lds[1][0];

// exp(s) + packed b64 swizzled P-write for sub-tile T into PW
#define EXPW(SV, T, PW)                                                          \
  do {                                                                           \
    const float p0 = fexp2((SV)[0]);                                             \
    const float p1 = fexp2((SV)[1]);                                             \
    const float p2 = fexp2((SV)[2]);                                             \
    const float p3 = fexp2((SV)[3]);                                             \
    lsum += (p0 + p1) + (p2 + p3);                                               \
    u32x2 pk;                                                                    \
    pk[0] = pack2(p0, p1);                                                       \
    pk[1] = pack2(p2, p3);                                                       \
    *(u32x2*)((PW) + (((2 * (T) + q4h) ^ (lr & 7)) * 8)) = pk;                   \
  } while (0)

  // --- prologue: Q(0)->bqA; DMA(0)->vt[0]; S^T(0)+exp+P->p_lds[0]; Q(1)->bqB
  short8 bqA[4], bqB[4];
#pragma unroll
  for (int t = 0; t < 4; t++)
    bqA[t] = *(const short8*)(q_base + (size_t)(t * 16 + lr) * CQK + q4 * 8);
#pragma unroll
  for (int ii = 0; ii < 8; ii++)
    gl_lds16(vt_g + (size_t)(ii * 32) * NTOK, &vt_lds[0][ii * 2048 + w * 512]);
  {
    f32x4 s0 = MFMA16(bqA[0], a_k, ((f32x4){0.f, 0.f, 0.f, 0.f}));
    f32x4 s1 = MFMA16(bqA[1], a_k, ((f32x4){0.f, 0.f, 0.f, 0.f}));
    f32x4 s2 = MFMA16(bqA[2], a_k, ((f32x4){0.f, 0.f, 0.f, 0.f}));
    f32x4 s3 = MFMA16(bqA[3], a_k, ((f32x4){0.f, 0.f, 0.f, 0.f}));
    u16* pwn = pl0 + pw_off;
    EXPW(s0, 0, pwn);
    EXPW(s1, 1, pwn);
    EXPW(s2, 2, pwn);
    EXPW(s3, 3, pwn);
  }
#pragma unroll
  for (int t = 0; t < 4; t++)
    bqB[t] = *(const short8*)(q_base + (size_t)(64 + t * 16 + lr) * CQK + q4 * 8);

// One pipelined iteration: barrier; DMA(JT+1); S^T(JT+1) from BQN regs;
// PV(JT) from PL_CUR/VB_CUR with exp(JT+1)->PL_NXT interleaved per ks;
// optionally prefetch Q(JT+2) into BQF.
#define ATTN_ITER(JT, PL_CUR, PL_NXT, VB_CUR, VB_NXT, BQN, BQF, DO_Q)            \
  do {                                                                           \
    const int j0 = (JT) * 64;                                                    \
    BAR_VMEM(); /* DMA(JT)+Q landed; P(JT) visible; iter JT-1 reads retired */   \
    _Pragma("unroll")                                                            \
    for (int ii = 0; ii < 8; ii++)                                               \
      gl_lds16(vt_g + (size_t)(ii * 32) * NTOK + (j0 + 64),                      \
               &VB_NXT[ii * 2048 + w * 512]);                                    \
    /* S^T(JT+1): register-only, fills the matrix pipe before PV reads land */   \
    f32x4 s0 = MFMA16(BQN[0], a_k, ((f32x4){0.f, 0.f, 0.f, 0.f}));               \
    f32x4 s1 = MFMA16(BQN[1], a_k, ((f32x4){0.f, 0.f, 0.f, 0.f}));               \
    f32x4 s2 = MFMA16(BQN[2], a_k, ((f32x4){0.f, 0.f, 0.f, 0.f}));               \
    f32x4 s3 = MFMA16(BQN[3], a_k, ((f32x4){0.f, 0.f, 0.f, 0.f}));               \
    u16* pwn = (PL_NXT) + pw_off;                                                \
    /* PV(JT) with exp(JT+1) interleaved: VALU rides under MFMA32 pipe */        \
    _Pragma("unroll")                                                            \
    for (int ks = 0; ks < 4; ks++) {                                             \
      const int slot = (((ks * 2 + Lhi) ^ L7)) * 8;                              \
      short8 a_p0 = *(const short8*)((PL_CUR) + L31 * 64 + slot);                \
      short8 a_p1 = *(const short8*)((PL_CUR) + (32 + L31) * 64 + slot);         \
      _Pragma("unroll")                                                          \
      for (int ct2 = 0; ct2 < 2; ct2++) {                                        \
        const int cl = w * 64 + ct2 * 32 + L31;                                  \
        short8 b_v = *(const short8*)((VB_CUR) + cl * 64 + slot);                \
        o_acc[0][ct2] = MFMA32(a_p0, b_v, o_acc[0][ct2]);                        \
        o_acc[1][ct2] = MFMA32(a_p1, b_v, o_acc[1][ct2]);                        \
      }                                                                          \
      if (ks == 0) EXPW(s0, 0, pwn);                                             \
      if (ks == 1) EXPW(s1, 1, pwn);                                             \
      if (ks == 2) EXPW(s2, 2, pwn);                                             \
      if (ks == 3) EXPW(s3, 3, pwn);                                             \
    }                                                                            \
    if (DO_Q) {                                                                  \
      _Pragma("unroll")                                                          \
      for (int t = 0; t < 4; t++)                                                \
        BQF[t] = *(const short8*)(q_base +                                       \
                 (size_t)(j0 + 128 + t * 16 + lr) * CQK + q4 * 8);               \
    }                                                                            \
  } while (0)

  for (int jt2 = 0; jt2 < 62; jt2 += 2) {
    ATTN_ITER(jt2,     pl0, pl1, (&vt_lds[0][0]), (&vt_lds[1][0]), bqB, bqA, 1);
    ATTN_ITER(jt2 + 1, pl1, pl0, (&vt_lds[1][0]), (&vt_lds[0][0]), bqA, bqB, 1);
  }
  // t=62: computes S(63)+P->pl1, DMA(63)->vt[1]; no Q(64) prefetch.
  ATTN_ITER(62, pl0, pl1, (&vt_lds[0][0]), (&vt_lds[1][0]), bqB, bqA, 0);
#undef ATTN_ITER

  // t=63: PV only.
  BAR_VMEM();
#pragma unroll
  for (int ks = 0; ks < 4; ks++) {
    const int slot = (((ks * 2 + Lhi) ^ L7)) * 8;
    short8 a_p0 = *(const short8*)(pl1 + L31 * 64 + slot);
    short8 a_p1 = *(const short8*)(pl1 + (32 + L31) * 64 + slot);
#pragma unroll
    for (int ct2 = 0; ct2 < 2; ct2++) {
      const int cl = w * 64 + ct2 * 32 + L31;
      short8 b_v = *(const short8*)(&vt_lds[1][0] + cl * 64 + slot);
      o_acc[0][ct2] = MFMA32(a_p0, b_v, o_acc[0][ct2]);
      o_acc[1][ct2] = MFMA32(a_p1, b_v, o_acc[1][ct2]);
    }
  }
#undef EXPW

  // softmax denominators (one i-row per lane; sum across q4 groups)
  float s2 = lsum;
  s2 += __shfl_xor(s2, 16);
  s2 += __shfl_xor(s2, 32);
  const float rl = 1.0f / s2;
  BAR_LDS();
  float* lp = (float*)pl0;
  if (q4 == 0) lp[w * 16 + lr] = rl;
  BAR_LDS();

  float linv2[2][16];
#pragma unroll
  for (int ih = 0; ih < 2; ih++)
#pragma unroll
    for (int rg = 0; rg < 16; rg++)
      linv2[ih][rg] = lp[ih * 32 + (rg & 3) + 8 * (rg >> 2) + 4 * Lhi];

  const float g = gamma[0];
#pragma unroll
  for (int ih = 0; ih < 2; ih++)
#pragma unroll
    for (int ct2 = 0; ct2 < 2; ct2++) {
      const int c = w * 64 + ct2 * 32 + L31;
#pragma unroll
      for (int rg = 0; rg < 16; rg++) {
        const int i = i0 + ih * 32 + (rg & 3) + 8 * (rg >> 2) + 4 * Lhi;
        const size_t idx = ((size_t)(b * NTOK + i)) * CDIM + c;
        out[idx] = g * (o_acc[ih][ct2][rg] * linv2[ih][rg]) + x[idx];
      }
    }
}

// ---------------------------------------------------------------------------
extern "C" void kernel_launch(void* const* d_in, const int* in_sizes, int n_in,
                              void* d_out, int out_size, void* d_ws, size_t ws_size,
                              hipStream_t stream) {
  const float* x  = (const float*)d_in[0];
  const float* Wq = (const float*)d_in[1];
  const float* bq = (const float*)d_in[2];
  const float* Wk = (const float*)d_in[3];
  const float* bk = (const float*)d_in[4];
  const float* Wv = (const float*)d_in[5];
  const float* bv = (const float*)d_in[6];
  const float* gamma = (const float*)d_in[7];
  float* out = (float*)d_out;

  char* ws = (char*)d_ws;
  u16* q_ws  = (u16*)(ws);
  u16* k_ws  = (u16*)(ws + (2u << 20));
  u16* vt_ws = (u16*)(ws + (4u << 20));
  u16* wtf   = (u16*)(ws + (20u << 20));
  float* bias = (float*)(ws + (20u << 20) + (256u << 10));

  k_prep<<<160, 64, 0, stream>>>(Wq, bq, Wk, bk, Wv, bv, wtf, bias);
  k_proj<<<512, 256, 0, stream>>>(x, wtf, bias, q_ws, k_ws, vt_ws);
  k_attn<<<512, 256, 0, stream>>>(x, q_ws, k_ws, vt_ws, gamma, out);
}

// Round 5
// 185.057 us; speedup vs baseline: 1.1960x; 1.0556x over previous
//
#include <hip/hip_runtime.h>

typedef __attribute__((ext_vector_type(8))) short short8;
typedef __attribute__((ext_vector_type(4))) float f32x4;
typedef __attribute__((ext_vector_type(16))) float f32x16;
typedef __attribute__((ext_vector_type(2))) unsigned int u32x2;
typedef __attribute__((ext_vector_type(4))) unsigned int u32x4;
typedef unsigned short u16;
typedef unsigned int u32;

#define MFMA16(a, b, c) __builtin_amdgcn_mfma_f32_16x16x32_bf16((a), (b), (c), 0, 0, 0)
#define MFMA32(a, b, c) __builtin_amdgcn_mfma_f32_32x32x16_bf16((a), (b), (c), 0, 0, 0)

#define BAR_VMEM() asm volatile("s_waitcnt vmcnt(0) lgkmcnt(0)\ns_barrier" ::: "memory")
#define BAR_LDS()  asm volatile("s_waitcnt lgkmcnt(0)\ns_barrier" ::: "memory")

#define BATCH 8
#define NTOK 4096
#define CDIM 256
#define CQK 32
#define LOG2E 1.4426950408889634f

__device__ __forceinline__ u16 f2bf(float f) {
  u32 u = __float_as_uint(f);
  return (u16)((u + 0x7FFFu + ((u >> 16) & 1u)) >> 16);
}
// pack two f32 -> two bf16 (round-half-up) in one u32: bf(a) | bf(b)<<16
__device__ __forceinline__ u32 pack2(float a, float b) {
  const u32 ua = __float_as_uint(a) + 0x8000u;
  const u32 ub = __float_as_uint(b) + 0x8000u;
#if __has_builtin(__builtin_amdgcn_perm)
  return __builtin_amdgcn_perm(ub, ua, 0x07060302u);  // {ua.b2,ua.b3,ub.b2,ub.b3}
#else
  return (ua >> 16) | (ub & 0xFFFF0000u);
#endif
}
__device__ __forceinline__ float fexp2(float x) {
#if __has_builtin(__builtin_amdgcn_exp2f)
  return __builtin_amdgcn_exp2f(x);
#else
  return exp2f(x);
#endif
}

// ---------------------------------------------------------------------------
// Kernel 0: weights -> MFMA B-fragment order + f32 bias.
// ---------------------------------------------------------------------------
__global__ void k_prep(const float* __restrict__ Wq, const float* __restrict__ bq,
                       const float* __restrict__ Wk, const float* __restrict__ bk,
                       const float* __restrict__ Wv, const float* __restrict__ bv,
                       u16* __restrict__ wtf, float* __restrict__ bias) {
  const int f = blockIdx.x;        // 0..159 = ct*8+ks
  const int L = threadIdx.x;       // 0..63
  const int ct = f >> 3, ks = f & 7;
  const int o = ct * 16 + (L & 15);
  const int ch = ks * 32 + (L >> 4) * 8;
  short8 v8;
#pragma unroll
  for (int jj = 0; jj < 8; jj++) {
    const int c = ch + jj;
    float v;
    if (o < 32)       v = Wq[c * CQK + o];
    else if (o < 64)  v = Wk[c * CQK + (o - 32)];
    else              v = Wv[c * CDIM + (o - 64)];
    v8[jj] = (short)f2bf(v);
  }
  *(short8*)(wtf + (size_t)f * 512 + L * 8) = v8;
  if (f == 0) {
    for (int i = L; i < 320; i += 64) {
      if (i < 32)      bias[i] = bq[i];
      else if (i < 64) bias[i] = bk[i - 32];
      else             bias[i] = bv[i - 64];
    }
  }
}

// ---------------------------------------------------------------------------
// Kernel 1: fused cvt+proj. K outputs pre-scaled by log2(e) (exp2 trick).
// V is emitted in FRAGMENT-LINEAR layout: for each (b, j-tile, wave w,
// frag fi=ks*2+ct2) the exact 1 KB that k_attn's 64 lanes consume as one
// MFMA32 B-fragment is stored contiguously (half-swap on channel bit3 baked
// in, matching the P-LDS half swizzle). k_attn then loads V global->reg
// fully coalesced with no LDS staging.
// Index: frag(b,jt,w,fi) at ((b*64+jt)*4+w)*8+fi, 512 u16 each; +lane*8.
// ---------------------------------------------------------------------------
__global__ __launch_bounds__(256, 2) void k_proj(
    const float* __restrict__ x, const u16* __restrict__ wtf,
    const float* __restrict__ bias,
    u16* __restrict__ q_ws, u16* __restrict__ k_ws, u16* __restrict__ vt_ws) {
  __shared__ u16 x_lds[64 * 264];
  __shared__ u16 vt_t[64 * 72];
  const int m0 = blockIdx.x * 64;
  const int tid = threadIdx.x;
  const int w = tid >> 6, L = tid & 63;
  const int lr = L & 15, q4 = L >> 4;

  // ks=0 weight prefetch (independent of LDS) — flies across the x staging.
  short8 wfA[5], wfB[5];
#pragma unroll
  for (int j = 0; j < 5; j++)
    wfA[j] = *(const short8*)(wtf + ((size_t)((j * 4 + w) * 8 + 0)) * 512 + L * 8);

  // stage + convert x tile via perm-packs
#pragma unroll
  for (int ii = 0; ii < 8; ii++) {
    const int e = (tid + 256 * ii) * 8;
    const int row = e >> 8, col = e & 255;
    const float* src = x + (size_t)(m0 + row) * CDIM + col;
    f32x4 a = *(const f32x4*)src;
    f32x4 b4 = *(const f32x4*)(src + 4);
    u32x4 pk;
    pk[0] = pack2(a[0], a[1]);
    pk[1] = pack2(a[2], a[3]);
    pk[2] = pack2(b4[0], b4[1]);
    pk[3] = pack2(b4[2], b4[3]);
    *(u32x4*)&x_lds[row * 264 + col] = pk;
  }
  __syncthreads();

  f32x4 acc[4][5];
#pragma unroll
  for (int rg = 0; rg < 4; rg++)
#pragma unroll
    for (int j = 0; j < 5; j++) acc[rg][j] = (f32x4){0.f, 0.f, 0.f, 0.f};

#pragma unroll
  for (int ks = 0; ks < 8; ks++) {
    // prefetch next ks-slice into the other buffer (no barriers in this loop)
    if (ks < 7) {
#pragma unroll
      for (int j = 0; j < 5; j++) {
        short8 v = *(const short8*)(wtf +
            ((size_t)((j * 4 + w) * 8 + ks + 1)) * 512 + L * 8);
        if (ks & 1) wfA[j] = v; else wfB[j] = v;
      }
    }
#pragma unroll
    for (int rg = 0; rg < 4; rg++) {
      short8 a = *(const short8*)&x_lds[(rg * 16 + lr) * 264 + ks * 32 + q4 * 8];
#pragma unroll
      for (int j = 0; j < 5; j++)
        acc[rg][j] = MFMA16(a, (ks & 1) ? wfB[j] : wfA[j], acc[rg][j]);
    }
  }

  // q/k epilogue (j=0 -> ct = w; k scaled by log2e). Branch is wave-uniform.
  {
    const float bb = bias[w * 16 + lr];
#pragma unroll
    for (int rg = 0; rg < 4; rg++)
#pragma unroll
      for (int r = 0; r < 4; r++) {
        const int row = m0 + rg * 16 + q4 * 4 + r;
        float v = acc[rg][0][r] + bb;
        if (w < 2) q_ws[(size_t)row * CQK + w * 16 + lr] = f2bf(v);
        else       k_ws[(size_t)row * CQK + (w - 2) * 16 + lr] = f2bf(v * LOG2E);
      }
  }
  // v epilogue: transpose via LDS with half-swap, then fragment-linear store.
  const int b = m0 >> 12, nt = (m0 & 4095) >> 6;
  const int rb2 = ((lr >> 3) & 1) << 2;       // row-bit3 of c_l = w*16+lr
  const int c_l = w * 16 + lr;
#pragma unroll
  for (int cg = 0; cg < 4; cg++) {
    __syncthreads();
    const int j = cg + 1;
    const float bb = bias[(4 + cg * 4 + w) * 16 + lr];
#pragma unroll
    for (int rg = 0; rg < 4; rg++) {
      const int n_base = (rg * 16 + q4 * 4) ^ rb2;  // half-swapped physical pos
      u32x2 pk;
      pk[0] = pack2(acc[rg][j][0] + bb, acc[rg][j][1] + bb);
      pk[1] = pack2(acc[rg][j][2] + bb, acc[rg][j][3] + bb);
      *(u32x2*)&vt_t[c_l * 72 + n_base] = pk;
    }
    __syncthreads();
    // fragment-linear store: consumer wave == cg; frag fi = ks*2+ct2;
    // lane holds channel ct2*32+(lane&31), j-window (ks*2+(lane>>5))*8..+8.
#pragma unroll
    for (int i = 0; i < 2; i++) {
      const int gch = tid + 256 * i;
      const int fi = gch >> 6;            // 0..7
      const int lane = gch & 63;
      const int ks2 = fi >> 1, ct2 = fi & 1;
      short8 v = *(const short8*)&vt_t[(ct2 * 32 + (lane & 31)) * 72 +
                                       (ks2 * 2 + (lane >> 5)) * 8];
      *(short8*)(vt_ws +
          ((((size_t)(b * 64 + nt) * 4 + cg) * 8 + fi) * 512) + lane * 8) = v;
    }
  }
}

// ---------------------------------------------------------------------------
// Kernel 2: flash attention, V direct global->register (no V LDS staging).
// V has zero cross-wave reuse (wave w owns channels w*64..+63), so LDS
// staging was pure overhead; fragment-linear vt_ws makes the per-lane loads
// perfectly coalesced (1 KB contiguous per fragment). Only P round-trips
// through LDS (4x cross-wave reuse), double-buffered; the loop barrier is
// now LDS-only — no vmcnt(0) drain in the hot loop. V(t+1) frags reload
// into the same register slots right after their last MFMA use.
// ---------------------------------------------------------------------------
__global__ __launch_bounds__(256, 2) void k_attn(
    const float* __restrict__ x, const u16* __restrict__ q_ws,
    const u16* __restrict__ k_ws, const u16* __restrict__ vt_ws,
    const float* __restrict__ gamma, float* __restrict__ out) {
  __shared__ u16 p_lds[2][64 * 64];     // 16 KB total

  const int bid = blockIdx.x;
  const int b = bid & 7;                // same-b blocks land on one XCD
  const int it = bid >> 3;
  const int i0 = it * 64;
  const int tid = threadIdx.x;
  const int w = tid >> 6, L = tid & 63;
  const int lr = L & 15, q4 = L >> 4;
  const int L31 = L & 31, Lhi = L >> 5, L7 = L & 7;

  const short8 a_k = *(const short8*)(k_ws +
      ((size_t)(b * NTOK + i0 + w * 16 + lr)) * CQK + q4 * 8);

  // V fragment base: frag(t, w, fi) at ((b*64+t)*4+w)*8+fi (512 u16 each)
  const u16* vg = vt_ws + (((size_t)b * 256 + w) * 8) * 512 + (size_t)L * 8;
  const u16* q_base = q_ws + (size_t)b * NTOK * CQK;

  f32x16 o_acc[2][2];
#pragma unroll
  for (int ih = 0; ih < 2; ih++)
#pragma unroll
    for (int ct2 = 0; ct2 < 2; ct2++)
#pragma unroll
      for (int e = 0; e < 16; e++) o_acc[ih][ct2][e] = 0.f;
  float lsum = 0.f;

  // P write base offset: row i = w*16+lr; half = (q4&1)^((i>>3)&1); chunk XOR.
  const int pw_off = (w * 16 + lr) * 64 + (((q4 & 1) ^ ((lr >> 3) & 1)) << 2);
  const int q4h = q4 >> 1;
  u16* const pl0 = &p_lds[0][0];
  u16* const pl1 = &p_lds[1][0];

// exp(s) + packed b64 swizzled P-write for sub-tile T into PW
#define EXPW(SV, T, PW)                                                          \
  do {                                                                           \
    const float p0 = fexp2((SV)[0]);                                             \
    const float p1 = fexp2((SV)[1]);                                             \
    const float p2 = fexp2((SV)[2]);                                             \
    const float p3 = fexp2((SV)[3]);                                             \
    lsum += (p0 + p1) + (p2 + p3);                                               \
    u32x2 pk;                                                                    \
    pk[0] = pack2(p0, p1);                                                       \
    pk[1] = pack2(p2, p3);                                                       \
    *(u32x2*)((PW) + (((2 * (T) + q4h) ^ (lr & 7)) * 8)) = pk;                   \
  } while (0)

  // --- prologue: Q(0)->bqA; V(0)->vV; S^T(0)+exp+P->pl0; Q(1)->bqB
  short8 bqA[4], bqB[4];
  short8 vV[8];
#pragma unroll
  for (int t = 0; t < 4; t++)
    bqA[t] = *(const short8*)(q_base + (size_t)(t * 16 + lr) * CQK + q4 * 8);
#pragma unroll
  for (int fi = 0; fi < 8; fi++)
    vV[fi] = *(const short8*)(vg + (size_t)fi * 512);
  {
    f32x4 s0 = MFMA16(bqA[0], a_k, ((f32x4){0.f, 0.f, 0.f, 0.f}));
    f32x4 s1 = MFMA16(bqA[1], a_k, ((f32x4){0.f, 0.f, 0.f, 0.f}));
    f32x4 s2 = MFMA16(bqA[2], a_k, ((f32x4){0.f, 0.f, 0.f, 0.f}));
    f32x4 s3 = MFMA16(bqA[3], a_k, ((f32x4){0.f, 0.f, 0.f, 0.f}));
    u16* pwn = pl0 + pw_off;
    EXPW(s0, 0, pwn);
    EXPW(s1, 1, pwn);
    EXPW(s2, 2, pwn);
    EXPW(s3, 3, pwn);
  }
#pragma unroll
  for (int t = 0; t < 4; t++)
    bqB[t] = *(const short8*)(q_base + (size_t)(64 + t * 16 + lr) * CQK + q4 * 8);

// One iteration: LDS-only barrier; S^T(JT+1) from BQN regs; Q(JT+2)->BQF;
// PV(JT) from PL_CUR + vV regs, with exp(JT+1)->PL_NXT and V(JT+1) reloads
// (into the just-freed vV slots) interleaved per ks.
#define ATTN_ITER(JT, PL_CUR, PL_NXT, BQN, BQF, DO_Q)                            \
  do {                                                                           \
    BAR_LDS(); /* all P(JT) writes visible; PL_NXT free for overwrite */         \
    f32x4 s0 = MFMA16(BQN[0], a_k, ((f32x4){0.f, 0.f, 0.f, 0.f}));               \
    f32x4 s1 = MFMA16(BQN[1], a_k, ((f32x4){0.f, 0.f, 0.f, 0.f}));               \
    f32x4 s2 = MFMA16(BQN[2], a_k, ((f32x4){0.f, 0.f, 0.f, 0.f}));               \
    f32x4 s3 = MFMA16(BQN[3], a_k, ((f32x4){0.f, 0.f, 0.f, 0.f}));               \
    if (DO_Q) {                                                                  \
      _Pragma("unroll")                                                          \
      for (int t = 0; t < 4; t++)                                                \
        BQF[t] = *(const short8*)(q_base +                                       \
                 (size_t)((JT) * 64 + 128 + t * 16 + lr) * CQK + q4 * 8);        \
    }                                                                            \
    u16* pwn = (PL_NXT) + pw_off;                                                \
    _Pragma("unroll")                                                            \
    for (int ks = 0; ks < 4; ks++) {                                             \
      const int slot = (((ks * 2 + Lhi) ^ L7)) * 8;                              \
      short8 a_p0 = *(const short8*)((PL_CUR) + L31 * 64 + slot);                \
      short8 a_p1 = *(const short8*)((PL_CUR) + (32 + L31) * 64 + slot);         \
      o_acc[0][0] = MFMA32(a_p0, vV[ks * 2 + 0], o_acc[0][0]);                   \
      o_acc[1][0] = MFMA32(a_p1, vV[ks * 2 + 0], o_acc[1][0]);                   \
      o_acc[0][1] = MFMA32(a_p0, vV[ks * 2 + 1], o_acc[0][1]);                   \
      o_acc[1][1] = MFMA32(a_p1, vV[ks * 2 + 1], o_acc[1][1]);                   \
      vV[ks * 2 + 0] = *(const short8*)(vg +                                     \
          (size_t)((JT) + 1) * 16384 + (ks * 2 + 0) * 512);                      \
      vV[ks * 2 + 1] = *(const short8*)(vg +                                     \
          (size_t)((JT) + 1) * 16384 + (ks * 2 + 1) * 512);                      \
      if (ks == 0) EXPW(s0, 0, pwn);                                             \
      if (ks == 1) EXPW(s1, 1, pwn);                                             \
      if (ks == 2) EXPW(s2, 2, pwn);                                             \
      if (ks == 3) EXPW(s3, 3, pwn);                                             \
    }                                                                            \
  } while (0)

  for (int jt2 = 0; jt2 < 62; jt2 += 2) {
    ATTN_ITER(jt2,     pl0, pl1, bqB, bqA, 1);
    ATTN_ITER(jt2 + 1, pl1, pl0, bqA, bqB, 1);
  }
  // t=62: computes S(63)+P->pl1, loads V(63); no Q(64) prefetch.
  ATTN_ITER(62, pl0, pl1, bqB, bqA, 0);
#undef ATTN_ITER

  // t=63: PV only.
  BAR_LDS();
#pragma unroll
  for (int ks = 0; ks < 4; ks++) {
    const int slot = (((ks * 2 + Lhi) ^ L7)) * 8;
    short8 a_p0 = *(const short8*)(pl1 + L31 * 64 + slot);
    short8 a_p1 = *(const short8*)(pl1 + (32 + L31) * 64 + slot);
    o_acc[0][0] = MFMA32(a_p0, vV[ks * 2 + 0], o_acc[0][0]);
    o_acc[1][0] = MFMA32(a_p1, vV[ks * 2 + 0], o_acc[1][0]);
    o_acc[0][1] = MFMA32(a_p0, vV[ks * 2 + 1], o_acc[0][1]);
    o_acc[1][1] = MFMA32(a_p1, vV[ks * 2 + 1], o_acc[1][1]);
  }
#undef EXPW

  // softmax denominators (one i-row per lane; sum across q4 groups)
  float s2 = lsum;
  s2 += __shfl_xor(s2, 16);
  s2 += __shfl_xor(s2, 32);
  const float rl = 1.0f / s2;
  BAR_LDS();
  float* lp = (float*)pl0;
  if (q4 == 0) lp[w * 16 + lr] = rl;
  BAR_LDS();

  float linv2[2][16];
#pragma unroll
  for (int ih = 0; ih < 2; ih++)
#pragma unroll
    for (int rg = 0; rg < 16; rg++)
      linv2[ih][rg] = lp[ih * 32 + (rg & 3) + 8 * (rg >> 2) + 4 * Lhi];

  const float g = gamma[0];
#pragma unroll
  for (int ih = 0; ih < 2; ih++)
#pragma unroll
    for (int ct2 = 0; ct2 < 2; ct2++) {
      const int c = w * 64 + ct2 * 32 + L31;
#pragma unroll
      for (int rg = 0; rg < 16; rg++) {
        const int i = i0 + ih * 32 + (rg & 3) + 8 * (rg >> 2) + 4 * Lhi;
        const size_t idx = ((size_t)(b * NTOK + i)) * CDIM + c;
        out[idx] = g * (o_acc[ih][ct2][rg] * linv2[ih][rg]) + x[idx];
      }
    }
}

// ---------------------------------------------------------------------------
extern "C" void kernel_launch(void* const* d_in, const int* in_sizes, int n_in,
                              void* d_out, int out_size, void* d_ws, size_t ws_size,
                              hipStream_t stream) {
  const float* x  = (const float*)d_in[0];
  const float* Wq = (const float*)d_in[1];
  const float* bq = (const float*)d_in[2];
  const float* Wk = (const float*)d_in[3];
  const float* bk = (const float*)d_in[4];
  const float* Wv = (const float*)d_in[5];
  const float* bv = (const float*)d_in[6];
  const float* gamma = (const float*)d_in[7];
  float* out = (float*)d_out;

  char* ws = (char*)d_ws;
  u16* q_ws  = (u16*)(ws);
  u16* k_ws  = (u16*)(ws + (2u << 20));
  u16* vt_ws = (u16*)(ws + (4u << 20));
  u16* wtf   = (u16*)(ws + (20u << 20));
  float* bias = (float*)(ws + (20u << 20) + (256u << 10));

  k_prep<<<160, 64, 0, stream>>>(Wq, bq, Wk, bk, Wv, bv, wtf, bias);
  k_proj<<<512, 256, 0, stream>>>(x, wtf, bias, q_ws, k_ws, vt_ws);
  k_attn<<<512, 256, 0, stream>>>(x, q_ws, k_ws, vt_ws, gamma, out);
}